// Round 14
// baseline (1441.125 us; speedup 1.0000x reference)
//
#include <hip/hip_runtime.h>

// y = alpha*(x @ Q^T) + bias; alpha = mean|W|; Q = clip(round(W/alpha),-1,1)
// x:(2,4096,4096) f32, W:(16384,4096) f32, bias:(16384) f32, out f32.
#define M_DIM 8192
#define N_DIM 16384
#define K_DIM 4096
#define NT 128  // K_DIM / 32

typedef unsigned short u16;
typedef unsigned int u32;
typedef __attribute__((ext_vector_type(8))) short bf16x8;
typedef __attribute__((ext_vector_type(8))) unsigned short u16x8;
typedef __attribute__((ext_vector_type(4))) float f32x4;

#define MFMA(a, b, c) __builtin_amdgcn_mfma_f32_16x16x32_bf16(a, b, c, 0, 0, 0)
#define SGB(mask, n) __builtin_amdgcn_sched_group_barrier((mask), (n), 0)

__device__ __forceinline__ void gload16(const u16* g, u16* l) {
  __builtin_amdgcn_global_load_lds((const __attribute__((address_space(1))) void*)g,
                                   (__attribute__((address_space(3))) void*)l, 16, 0, 0);
}

// ---------------- alpha = mean(|W|), f64 two-pass reduction ----------------
__global__ void reduce_abs1(const float* __restrict__ w, double* __restrict__ partials) {
  const float4* w4 = (const float4*)w;
  size_t base = (size_t)blockIdx.x * 4096 + threadIdx.x;
  double s = 0.0;
#pragma unroll
  for (int i = 0; i < 16; ++i) {
    float4 v = w4[base + (size_t)i * 256];
    s += (double)fabsf(v.x); s += (double)fabsf(v.y);
    s += (double)fabsf(v.z); s += (double)fabsf(v.w);
  }
#pragma unroll
  for (int off = 32; off > 0; off >>= 1) s += __shfl_down(s, off, 64);
  __shared__ double red[4];
  int wv = threadIdx.x >> 6, lane = threadIdx.x & 63;
  if (lane == 0) red[wv] = s;
  __syncthreads();
  if (threadIdx.x == 0) partials[blockIdx.x] = (red[0] + red[1]) + (red[2] + red[3]);
}

__global__ void reduce_abs2(const double* __restrict__ partials,
                            double* __restrict__ alpha_d, float* __restrict__ alpha_f) {
  double s = 0.0;
  for (int i = threadIdx.x; i < 4096; i += 256) s += partials[i];
#pragma unroll
  for (int off = 32; off > 0; off >>= 1) s += __shfl_down(s, off, 64);
  __shared__ double red[4];
  int wv = threadIdx.x >> 6, lane = threadIdx.x & 63;
  if (lane == 0) red[wv] = s;
  __syncthreads();
  if (threadIdx.x == 0) {
    double total = (red[0] + red[1]) + (red[2] + red[3]);
    double a = total / (double)((long long)N_DIM * (long long)K_DIM);
    alpha_d[0] = a;
    alpha_f[0] = (float)a;
  }
}

// ---------------- W -> ternary Q stored as bf16 (+1/0/-1 exact) ----------------
__global__ void quant_w(const float* __restrict__ w, const double* __restrict__ alpha_d,
                        u16* __restrict__ q) {
  double inv = 1.0 / alpha_d[0];
  size_t i8 = (size_t)blockIdx.x * 256 + threadIdx.x;
  const float4* w4 = (const float4*)w;
  float4 v0 = w4[i8 * 2], v1 = w4[i8 * 2 + 1];
  float vv[8] = {v0.x, v0.y, v0.z, v0.w, v1.x, v1.y, v1.z, v1.w};
  u16x8 o;
#pragma unroll
  for (int j = 0; j < 8; ++j) {
    double r = rint((double)vv[j] * inv);
    u16 enc = 0;
    if (r >= 1.0) enc = 0x3F80u;
    else if (r <= -1.0) enc = 0xBF80u;
    o[j] = enc;
  }
  *((u16x8*)q + i8) = o;
}

// ---------------- x fp32 -> bf16 (RNE) ----------------
__global__ void conv_x(const float* __restrict__ x, u16* __restrict__ xb) {
  size_t i8 = (size_t)blockIdx.x * 256 + threadIdx.x;
  const float4* x4 = (const float4*)x;
  float4 v0 = x4[i8 * 2], v1 = x4[i8 * 2 + 1];
  float vv[8] = {v0.x, v0.y, v0.z, v0.w, v1.x, v1.y, v1.z, v1.w};
  u16x8 o;
#pragma unroll
  for (int j = 0; j < 8; ++j) {
    u32 u = __float_as_uint(vv[j]);
    u += 0x7FFFu + ((u >> 16) & 1u);
    o[j] = (u16)(u >> 16);
  }
  *((u16x8*)xb + i8) = o;
}

// --- 128x128-block bf16 GEMM: 2 waves/block, 4 blocks/CU (multi-block overlap) ---
// Wave tile 128x64 (identical per-wave work to R13: 12 ds_reads + 32 MFMA per
// K-tile(32)); block = 2 waves (1M x 2N), 128 threads; BK=32 double-buffer ->
// 32 KiB LDS/block -> 4 blocks/CU (reg-capped: 128 AGPR acc + ~80 VGPR at
// 2 waves/SIMD). Rationale: 13 rounds of intra-block scheduling all landed
// 42-50% MfmaUtil -- one barrier domain makes the whole block alternate
// pipes. 4 independent 2-wave barrier domains per CU let one block's MFMA
// cover another's LDS/vmcnt stalls (m114: separate blocks overlap fully).
// Keeps: R13 conflict-free BK=32 XOR swizzle (SQ_LDS_BANK_CONFLICT == 0),
// SGB batch interleave, opposite-parity staging (stage kt+1 while computing
// kt: never aliases), single tile-end vmcnt(0)+barrier (2-wave barrier,
// drain covered by sibling blocks), XCD swizzle + supertiles (8192 %8==0).
__global__ __launch_bounds__(128, 2) void gemm128(
    const u16* __restrict__ A, const u16* __restrict__ Bq,
    const float* __restrict__ bias, const float* __restrict__ alpha_f,
    float* __restrict__ C) {
  __shared__ __align__(16) u16 Alds[2][128 * 32];  // 8 KiB per buffer
  __shared__ __align__(16) u16 Blds[2][128 * 32];

  const int t = threadIdx.x;
  const int wc = t >> 6, l = t & 63;   // 2 waves: wc = N-half
  const int lr = l & 15, lk = l >> 4;

  // XCD-bijective swizzle (8192 % 8 == 0) + 8(tm) x 128(tn) supertiles
  const int bid = blockIdx.x;
  const int wg = (bid & 7) * 1024 + (bid >> 3);
  const int grp = wg >> 10, rem = wg & 1023;
  const int tm = grp * 8 + (rem & 7);  // 0..63
  const int tn = rem >> 3;             // 0..127

  const u16* Ag = A + (size_t)tm * 128 * K_DIM;
  const u16* Bg = Bq + (size_t)tn * 128 * K_DIM;

  // Staging: 16B chunk q in [0,512) of a [128][32] tile: row=q>>2, physical
  // chunk pc=q&3 holds logical c = pc ^ ((row>>1)&3) (involution; R13-proven
  // conflict-free). Thread t owns q = s*128 + t, s=0..3. LDS dest linear.
  int so[4], dof[4];
#pragma unroll
  for (int s = 0; s < 4; ++s) {
    int q = s * 128 + t;
    int row = q >> 2, c = (q & 3) ^ ((row >> 1) & 3);
    so[s] = row * K_DIM + c * 8;
    dof[s] = (s * 128 + wc * 64) * 8;  // u16 units (wave-uniform dest base)
  }

  // Frag read base (u16): row = sub*16 + lr, chunk lk^((lr>>1)&3);
  // sub offsets (multiples of 16 rows) fold to immediates.
  const int fb = lr * 32 + ((lk ^ ((lr >> 1) & 3)) * 8);
#define LDA(b, m) (*(const bf16x8*)(&Alds[b][(m) * 512 + fb]))
#define LDB(b, n) (*(const bf16x8*)(&Blds[b][wc * 2048 + (n) * 512 + fb]))

  f32x4 acc[8][4];
#pragma unroll
  for (int mi = 0; mi < 8; ++mi)
#pragma unroll
    for (int ni = 0; ni < 4; ++ni)
      acc[mi][ni] = (f32x4){0.f, 0.f, 0.f, 0.f};

  // stage K-tile g into buffer g&1 (A: 4 gloads; B: 4 gloads per thread)
  auto stageA = [&](int g) {
    if (g < NT) {
      const u16* src = Ag + g * 32;
#pragma unroll
      for (int s = 0; s < 4; ++s) gload16(src + so[s], &Alds[g & 1][dof[s]]);
    }
  };
  auto stageB = [&](int g) {
    if (g < NT) {
      const u16* src = Bg + g * 32;
#pragma unroll
      for (int s = 0; s < 4; ++s) gload16(src + so[s], &Blds[g & 1][dof[s]]);
    }
  };

#define MFMA4(m0, m1, n0, n1, aset, bset)                                      \
  acc[m0][n0] = MFMA(aset[0], bset[0], acc[m0][n0]);                           \
  acc[m0][n1] = MFMA(aset[0], bset[1], acc[m0][n1]);                           \
  acc[m1][n0] = MFMA(aset[1], bset[0], acc[m1][n0]);                           \
  acc[m1][n1] = MFMA(aset[1], bset[1], acc[m1][n1])

  // one K-tile; b = kt&1 compile-time at each expansion
#define K_TILE(kt, b)                                                          \
  {                                                                            \
    bf16x8 a01[2], a23[2], a45[2], a67[2], b01[2], b23[2];                     \
    /* pre: A0,A1,B0,B1 */                                                     \
    a01[0] = LDA(b, 0); a01[1] = LDA(b, 1);                                    \
    b01[0] = LDB(b, 0); b01[1] = LDB(b, 1);                                    \
    SGB(0x100, 4);                                                             \
    /* b0: R{A2,A3,B2}; stage A(kt+1); M{A01 x B01} */                         \
    a23[0] = LDA(b, 2); a23[1] = LDA(b, 3);                                    \
    b23[0] = LDB(b, 2);                                                        \
    stageA((kt) + 1);                                                          \
    MFMA4(0, 1, 0, 1, a01, b01);                                               \
    SGB(0x100, 3); SGB(0x20, 4); SGB(0x8, 4);                                  \
    /* b1: R{A4,A5,B3}; stage B(kt+1); M{A23 x B01} */                         \
    a45[0] = LDA(b, 4); a45[1] = LDA(b, 5);                                    \
    b23[1] = LDB(b, 3);                                                        \
    stageB((kt) + 1);                                                          \
    MFMA4(2, 3, 0, 1, a23, b01);                                               \
    SGB(0x100, 3); SGB(0x20, 4); SGB(0x8, 4);                                  \
    /* b2: R{A6,A7}; M{A01 x B23} */                                           \
    a67[0] = LDA(b, 6); a67[1] = LDA(b, 7);                                    \
    MFMA4(0, 1, 2, 3, a01, b23);                                               \
    SGB(0x100, 2); SGB(0x8, 4);                                                \
    /* b3-b7: remaining MFMA quads */                                          \
    MFMA4(2, 3, 2, 3, a23, b23);                                               \
    SGB(0x8, 4);                                                               \
    MFMA4(4, 5, 0, 1, a45, b01);                                               \
    SGB(0x8, 4);                                                               \
    MFMA4(4, 5, 2, 3, a45, b23);                                               \
    SGB(0x8, 4);                                                               \
    MFMA4(6, 7, 0, 1, a67, b01);                                               \
    SGB(0x8, 4);                                                               \
    MFMA4(6, 7, 2, 3, a67, b23);                                               \
    SGB(0x8, 4);                                                               \
    /* tile end: our 8 loads (issued at tile top) must land; 2-wave barrier.  \
       Drain stall is covered by the other 3 blocks on this CU. */             \
    asm volatile("s_waitcnt vmcnt(0)" ::: "memory");                           \
    __builtin_amdgcn_s_barrier();                                              \
  }

  // prologue: stage tile 0 into buffer 0
  stageA(0); stageB(0);
  asm volatile("s_waitcnt vmcnt(0)" ::: "memory");
  __builtin_amdgcn_s_barrier();

  for (int kt2 = 0; kt2 < NT; kt2 += 2) {
    K_TILE(kt2 + 0, 0);
    K_TILE(kt2 + 1, 1);
  }
#undef K_TILE
#undef MFMA4
#undef LDA
#undef LDB

  // epilogue: y = alpha*acc + bias.  C/D: col=l&15, row=4*(l>>4)+j (m89-verified)
  const float alpha = alpha_f[0];
#pragma unroll
  for (int ni = 0; ni < 4; ++ni) {
    const int col = tn * 128 + wc * 64 + ni * 16 + lr;
    const float bs = bias[col];
#pragma unroll
    for (int mi = 0; mi < 8; ++mi) {
      const int row = tm * 128 + mi * 16 + lk * 4;
      float* Cp = C + (size_t)row * N_DIM + col;
#pragma unroll
      for (int j = 0; j < 4; ++j)
        Cp[(size_t)j * N_DIM] = alpha * acc[mi][ni][j] + bs;
    }
  }
}

extern "C" void kernel_launch(void* const* d_in, const int* in_sizes, int n_in,
                              void* d_out, int out_size, void* d_ws, size_t ws_size,
                              hipStream_t stream) {
  const float* x = (const float*)d_in[0];
  const float* w = (const float*)d_in[1];
  const float* bias = (const float*)d_in[2];
  float* out = (float*)d_out;

  char* ws = (char*)d_ws;
  double* alpha_d = (double*)ws;
  float* alpha_f = (float*)(ws + 8);
  double* partials = (double*)(ws + 16);
  u16* xb = (u16*)(ws + 65536);                 // 64 MiB (M*K bf16)
  u16* qb = (u16*)(ws + 65536 + 67108864ULL);   // 128 MiB (N*K bf16)

  reduce_abs1<<<4096, 256, 0, stream>>>(w, partials);
  reduce_abs2<<<1, 256, 0, stream>>>(partials, alpha_d, alpha_f);
  quant_w<<<32768, 256, 0, stream>>>(w, alpha_d, qb);
  conv_x<<<16384, 256, 0, stream>>>(x, xb);
  gemm128<<<8192, 128, 0, stream>>>(xb, qb, bias, alpha_f, out);
}